// Round 10
// baseline (294.820 us; speedup 1.0000x reference)
//
#include <hip/hip_runtime.h>

// SNN membrane scan + spike + double-cumsum, barrier-free producer/consumer.
//
// 256 blocks x 320 threads (5 waves), 64 channels/block.
//   wave 0    = scan: 4 named 8-timestep register windows, depth-4 continuous
//               load pipeline (48-64 loads always in flight, compiler-counted
//               vmcnt waits, NO manual drains, NO stores on this wave).
//               Publishes float(Z) per timestep into a 16-segment LDS ring,
//               signals via volatile flag after lgkmcnt(0).
//   waves 1-4 = writers: poll flag, ds_read ring slot, 4 float4 stores per
//               segment (2 arrays x 2 row-quads). Round-robin segments;
//               per-writer done-counters give ring backpressure.
// No __syncthreads / s_barrier in the main loop -> waves drift, HBM traffic
// de-bursts, scan read pipeline never drains.
//
// fmaf order + integer cumsums identical to prior passing kernels -> bit-exact.
// gz test (Z==1) on float is exact: Z < 2^21.

#define T_LEN 1024
#define N_IN  512
#define BN    16384          // BATCH * N_IN
#define ST    8              // timesteps per segment
#define NSEG  (T_LEN / ST)   // 128
#define RING  16             // zbuf ring depth (segments) = 128 t of slack
#define NW    4              // writer waves

__global__ __launch_bounds__(320, 1) void snn_fused(
        const float* __restrict__ cur, const float* __restrict__ beta,
        const float* __restrict__ vini, const float* __restrict__ vth,
        float* __restrict__ gz, float* __restrict__ zo, float* __restrict__ ml)
{
    __shared__ float zring[RING][ST][64];   // 32 KB: float(Z) ring
    __shared__ volatile int seg_ready;      // segments published by scan
    __shared__ volatile int wdone[NW];      // per-writer consumed count

    const int lane   = threadIdx.x & 63;
    const int wave   = threadIdx.x >> 6;    // 0 = scan, 1..4 = writers
    const int chbase = blockIdx.x * 64;

    if (threadIdx.x == 0) seg_ready = 0;
    if (threadIdx.x < NW) wdone[threadIdx.x] = 0;
    __syncthreads();                        // one-time init barrier

    if (wave == 0) {
        // ------------------------- scan wave ---------------------------------
        const int i = chbase + lane;
        const float bta = beta[i & (N_IN - 1)];
        float m = vini[i];
        int C = 0, Z = 0;
        const float* __restrict__ cp = cur + i;
        const float* __restrict__ vp = vth + i;

        float c0[ST], v0[ST], c1[ST], v1[ST];
        float c2[ST], v2[ST], c3[ST], v3[ST];   // 64 window floats

#define LOADW(cw, vw, q) do {                                              \
        const float* __restrict__ _c = cp + (size_t)(q) * ST * BN;         \
        const float* __restrict__ _v = vp + (size_t)(q) * ST * BN;         \
        _Pragma("unroll")                                                  \
        for (int _t = 0; _t < ST; ++_t) {                                  \
            cw[_t] = _c[(size_t)_t * BN];                                  \
            vw[_t] = _v[(size_t)_t * BN];                                  \
        } } while (0)

        // chain one segment out of registers, publish to ring, raise flag
#define CHAINW(cw, vw, s) do {                                             \
        float* _zb = &zring[(s) & (RING - 1)][0][lane];                    \
        _Pragma("unroll")                                                  \
        for (int _t = 0; _t < ST; ++_t) {                                  \
            m = fmaf(bta, m, cw[_t]);             /* exact op/order */     \
            const int _sp = (m >= vw[_t]) ? 1 : 0;                         \
            C += _sp;                             /* c1 cumsum (int) */    \
            Z += C;                               /* z dbl-cumsum   */     \
            _zb[_t * 64] = (float)Z;                                       \
        }                                                                  \
        asm volatile("s_waitcnt lgkmcnt(0)" ::: "memory");                 \
        seg_ready = (s) + 1; } while (0)

        // refill window with segment s+4 (ring backpressure check first)
#define REFILL(cw, vw, s) do {                                             \
        const int _q = (s) + 4;                                            \
        if (_q < NSEG) {                                                   \
            if (_q >= RING) {                                              \
                const int _r = _q & (NW - 1);                              \
                const int _need = (_q >> 2) - 3;  /* seg _q-16 consumed */ \
                while (wdone[_r] < _need) __builtin_amdgcn_s_sleep(1);     \
            }                                                              \
            LOADW(cw, vw, _q);                                             \
        } } while (0)

        LOADW(c0, v0, 0); LOADW(c1, v1, 1);
        LOADW(c2, v2, 2); LOADW(c3, v3, 3);     // 64 loads in flight

#pragma unroll 1
        for (int k = 0; k < NSEG / 4; ++k) {
            const int s = 4 * k;
            CHAINW(c0, v0, s);     REFILL(c0, v0, s);
            CHAINW(c1, v1, s + 1); REFILL(c1, v1, s + 1);
            CHAINW(c2, v2, s + 2); REFILL(c2, v2, s + 2);
            CHAINW(c3, v3, s + 3); REFILL(c3, v3, s + 3);
        }
        ml[i] = m;                              // m_last (B,N)
#undef LOADW
#undef CHAINW
#undef REFILL
    } else {
        // ------------------------- writer waves ------------------------------
        const int w       = wave - 1;           // 0..3
        const int row_sub = lane >> 4;          // 0..3 (rows r and r+4)
        const int chgrp   = lane & 15;          // channels 4*chgrp..+3
        int cnt = 0;

        for (int s = w; s < NSEG; s += NW) {
            while (seg_ready <= s) __builtin_amdgcn_s_sleep(1);
            asm volatile("" ::: "memory");      // order: flag before data reads
            const int sl = s & (RING - 1);
            const float4 za = *reinterpret_cast<const float4*>(
                                  &zring[sl][row_sub][4 * chgrp]);
            const float4 zb = *reinterpret_cast<const float4*>(
                                  &zring[sl][row_sub + 4][4 * chgrp]);
            // ds_reads complete before signaling slot free:
            asm volatile("s_waitcnt lgkmcnt(0)" ::: "memory");
            ++cnt;
            wdone[w] = cnt;                     // uniform value, all lanes

            const float4 ga = make_float4(za.x == 1.0f ? 1.0f : 0.0f,
                                          za.y == 1.0f ? 1.0f : 0.0f,
                                          za.z == 1.0f ? 1.0f : 0.0f,
                                          za.w == 1.0f ? 1.0f : 0.0f);
            const float4 gb = make_float4(zb.x == 1.0f ? 1.0f : 0.0f,
                                          zb.y == 1.0f ? 1.0f : 0.0f,
                                          zb.z == 1.0f ? 1.0f : 0.0f,
                                          zb.w == 1.0f ? 1.0f : 0.0f);
            const size_t offa = (size_t)(s * ST + row_sub) * BN
                              + chbase + 4 * chgrp;
            const size_t offb = offa + (size_t)4 * BN;
            *reinterpret_cast<float4*>(gz + offa) = ga;   // Block.g fwd value
            *reinterpret_cast<float4*>(gz + offb) = gb;
            *reinterpret_cast<float4*>(zo + offa) = za;   // exact: z < 2^21
            *reinterpret_cast<float4*>(zo + offb) = zb;
            // stores never drained in-loop; kernel end drains them.
        }
    }
}

extern "C" void kernel_launch(void* const* d_in, const int* in_sizes, int n_in,
                              void* d_out, int out_size, void* d_ws, size_t ws_size,
                              hipStream_t stream) {
    const float* cur  = (const float*)d_in[0];   // (T,B,N) fp32
    const float* beta = (const float*)d_in[1];   // (N,)
    const float* vini = (const float*)d_in[2];   // (B,N)
    const float* vth  = (const float*)d_in[3];   // (T,B,N)
    float* gz = (float*)d_out;                       // (T,B,N)
    float* zo = gz + (size_t)T_LEN * BN;             // (T,B,N)
    float* ml = zo + (size_t)T_LEN * BN;             // (B,N)

    snn_fused<<<BN / 64, 320, 0, stream>>>(cur, beta, vini, vth, gz, zo, ml);
}

// Round 11
// 267.254 us; speedup vs baseline: 1.1031x; 1.1031x over previous
//
#include <hip/hip_runtime.h>

// SNN membrane scan + spike + double-cumsum, two-pass wide-granule design.
//
// Evidence from R7-R10: any structure streaming 256 B granules caps at
// 2.45 TB/s (201.5 MB -> 82 us). R4's expand (1 KB granules, 32 waves/CU)
// ran ~5 TB/s. So: make every heavy stream 1 KB.
//
// Pass 1  snn_scan_wide  (64 blk x 768 thr = 12 waves, 256 ch/block):
//   waves 4-11: loaders. float4 global loads (1 KB/instr) -> transposed LDS
//               ring stage[a][slot][ch][17] (pad 17 -> scan reads conflict-free)
//               4-deep, 16-t segments; flag publish after lgkmcnt(0).
//   waves 0-3:  scan waves, 64 channels each (4 independent chains in parallel).
//               Per segment: 32 independent ds_read_b32 (latency pipelined, NOT
//               on the chain), then 16 exact chain steps. Emits spike bitmask
//               (1 bit/t) + packed carry C|Z<<11 every 32 t (R4-verified format).
// Pass 2  snn_expand  (2048 blk x 256 thr): verbatim R4 (verified): replay <=31
//   exact int steps from carry snapshot, stream float4 stores (1 KB/instr).
// Fallback (ws < 4 MB): R1-style single-kernel two-phase (verified, no ws).
//
// fmaf order + integer cumsums identical to all passing rounds -> bit-exact.

#define T_LEN 1024
#define N_IN  512
#define BN    16384           // BATCH * N_IN
#define DW    (T_LEN / 32)    // 32 bit-dwords per channel

// ---- pass 1 geometry ----
#define CHB   256             // channels per block
#define NBLK1 (BN / CHB)      // 64 blocks
#define SEGT  16              // timesteps per segment
#define NSEG1 (T_LEN / SEGT)  // 64 segments
#define RING1 4               // ring depth (per array)
#define TPAD  17              // padded t-stride (floats): bank=(17ch+t)%32

__global__ __launch_bounds__(768, 1) void snn_scan_wide(
        const float* __restrict__ cur, const float* __restrict__ beta,
        const float* __restrict__ vini, const float* __restrict__ vth,
        unsigned* __restrict__ bitsg, unsigned* __restrict__ Pc,
        float* __restrict__ ml)
{
    // stage[a][slot][ch][TPAD] : 2*4*256*17*4 B = 136 KB
    __shared__ float stage[2 * RING1 * CHB * TPAD];
    __shared__ volatile int prod[2][RING1];   // produced seg+1 per (array,slot)
    __shared__ volatile int scons[4];         // consumed count per scan wave

    const int lane   = threadIdx.x & 63;
    const int wave   = threadIdx.x >> 6;      // 0..3 scan, 4..11 loaders
    const int chbase = blockIdx.x * CHB;

    if (threadIdx.x < 8)  prod[threadIdx.x & 1][threadIdx.x >> 1] = 0;
    if (threadIdx.x < 4)  scons[threadIdx.x] = 0;
    __syncthreads();                          // one-time init

    if (wave >= 4) {
        // ----------------------------- loaders ------------------------------
        const int w = wave - 4;               // 0..7
        const int a = w & 1;                  // 0 = cur, 1 = vth
        const int r = w >> 1;                 // slot residue 0..3
        const float* __restrict__ src = (a == 0) ? cur : vth;

        for (int s = r; s < NSEG1; s += RING1) {
            if (s >= RING1) {                 // wait: slot's old seg consumed
                const int need = s - RING1 + 1;
                while (scons[0] < need || scons[1] < need ||
                       scons[2] < need || scons[3] < need)
                    __builtin_amdgcn_s_sleep(1);
                asm volatile("" ::: "memory");
            }
            // 16 x 1KB float4 row loads (t = s*16 .. +15), lane covers 4 ch
            float4 rg[SEGT];
#pragma unroll
            for (int t = 0; t < SEGT; ++t)
                rg[t] = *reinterpret_cast<const float4*>(
                            src + (size_t)(s * SEGT + t) * BN + chbase + 4 * lane);
            // transposed LDS scatter: stage[a][s&3][4*lane+j][t]
            float* base = &stage[((a * RING1 + (s & (RING1 - 1))) * CHB
                                  + 4 * lane) * TPAD];
#pragma unroll
            for (int t = 0; t < SEGT; ++t) {
                base[0 * TPAD + t] = rg[t].x;
                base[1 * TPAD + t] = rg[t].y;
                base[2 * TPAD + t] = rg[t].z;
                base[3 * TPAD + t] = rg[t].w;
            }
            asm volatile("s_waitcnt lgkmcnt(0)" ::: "memory");  // writes landed
            prod[a][s & (RING1 - 1)] = s + 1;                   // publish
        }
    } else {
        // ----------------------------- scan waves ---------------------------
        const int i = chbase + 64 * wave + lane;   // global channel
        const int chl = 64 * wave + lane;          // local channel 0..255
        const float bta = beta[i & (N_IN - 1)];
        float m = vini[i];
        int C = 0, Z = 0;
        unsigned mlo = 0u;

        const float* cbase = &stage[(0 * RING1 * CHB + chl) * TPAD];
        const float* vbase = &stage[(1 * RING1 * CHB + chl) * TPAD];

#pragma unroll 1
        for (int s = 0; s < NSEG1; ++s) {
            const int sl = s & (RING1 - 1);
            while (prod[0][sl] < s + 1 || prod[1][sl] < s + 1)
                __builtin_amdgcn_s_sleep(1);
            asm volatile("" ::: "memory");

            if ((s & 1) == 0)   // carry state BEFORE t = 32*(s/2)
                Pc[(size_t)(s >> 1) * BN + i] = (unsigned)C | ((unsigned)Z << 11);

            // 32 independent ds_read_b32: latency pipelined OFF the chain
            const float* lc = cbase + sl * CHB * TPAD;
            const float* lv = vbase + sl * CHB * TPAD;
            float cc[SEGT], vv[SEGT];
#pragma unroll
            for (int t = 0; t < SEGT; ++t) { cc[t] = lc[t]; vv[t] = lv[t]; }

            unsigned mask = 0u;
#pragma unroll
            for (int t = 0; t < SEGT; ++t) {
                m = fmaf(bta, m, cc[t]);              // exact same op/order
                const int sp = (m >= vv[t]) ? 1 : 0;  // Heaviside(m - vth)
                mask |= (unsigned)sp << t;
                C += sp;                              // c1 cumsum (exact int)
                Z += C;                               // z double-cumsum (exact)
            }
            if ((s & 1) == 0) {
                mlo = mask;
            } else {
                bitsg[(size_t)(s >> 1) * BN + i] = mlo | (mask << 16);
            }
            // reads complete (values consumed); release slot
            asm volatile("s_waitcnt lgkmcnt(0)" ::: "memory");
            if (lane == 0) scons[wave] = s + 1;
        }
        ml[i] = m;                                    // m_last (B,N)
    }
}

// -------------------------- pass 2: expand (R4, verified) -------------------
__global__ __launch_bounds__(256, 4) void snn_expand(
        const unsigned* __restrict__ bitsg, const unsigned* __restrict__ Pc,
        float* __restrict__ gz, float* __restrict__ zo)
{
    const int d  = blockIdx.x & (DW - 1);   // t-dword 0..31
    const int cb = blockIdx.x / DW;         // channel block 0..63
    const int cg = threadIdx.x & 63;        // 4-channel group within 256
    const int tt = threadIdx.x >> 6;        // wave id 0..3 -> owns 8 t-rows
    const int ch = cb * 256 + cg * 4;       // first of 4 consecutive channels

    const uint4 u  = *reinterpret_cast<const uint4*>(&bitsg[(size_t)d * BN + ch]);
    const uint4 p4 = *reinterpret_cast<const uint4*>(&Pc[(size_t)d * BN + ch]);
    int C0 = (int)(p4.x & 0x7FFu), Z0 = (int)(p4.x >> 11);
    int C1 = (int)(p4.y & 0x7FFu), Z1 = (int)(p4.y >> 11);
    int C2 = (int)(p4.z & 0x7FFu), Z2 = (int)(p4.z >> 11);
    int C3 = (int)(p4.w & 0x7FFu), Z3 = (int)(p4.w >> 11);

    const int pre = tt * 8;                 // replay bits [0, pre) exactly
    for (int b = 0; b < pre; ++b) {
        C0 += (int)((u.x >> b) & 1u); Z0 += C0;
        C1 += (int)((u.y >> b) & 1u); Z1 += C1;
        C2 += (int)((u.z >> b) & 1u); Z2 += C2;
        C3 += (int)((u.w >> b) & 1u); Z3 += C3;
    }

    float* __restrict__ gp = gz + (size_t)(d * 32 + pre) * BN + ch;
    float* __restrict__ zp = zo + (size_t)(d * 32 + pre) * BN + ch;
#pragma unroll
    for (int r = 0; r < 8; ++r) {           // my 8 t-rows: t = 32d + pre + r
        const int b = pre + r;
        C0 += (int)((u.x >> b) & 1u); Z0 += C0;
        C1 += (int)((u.y >> b) & 1u); Z1 += C1;
        C2 += (int)((u.z >> b) & 1u); Z2 += C2;
        C3 += (int)((u.w >> b) & 1u); Z3 += C3;
        const float4 gf = make_float4(Z0 == 1 ? 1.0f : 0.0f,
                                      Z1 == 1 ? 1.0f : 0.0f,
                                      Z2 == 1 ? 1.0f : 0.0f,
                                      Z3 == 1 ? 1.0f : 0.0f);
        const float4 zf = make_float4((float)Z0, (float)Z1,
                                      (float)Z2, (float)Z3);
        *reinterpret_cast<float4*>(gp + (size_t)r * BN) = gf;   // Block.g fwd
        *reinterpret_cast<float4*>(zp + (size_t)r * BN) = zf;   // exact: z < 2^21
    }
}

// ---------------------- fallback (no workspace; R1-verified) ----------------
#define U 16
struct Buf { float c[U]; float v[U]; };

__device__ __forceinline__ void prefetch(Buf& b, const float* __restrict__ cp,
                                         const float* __restrict__ vp, int t0) {
    if (t0 >= T_LEN) return;
    const float* __restrict__ c = cp + (size_t)t0 * BN;
    const float* __restrict__ v = vp + (size_t)t0 * BN;
#pragma unroll
    for (int u = 0; u < U; ++u) {
        b.c[u] = c[(size_t)u * BN];
        b.v[u] = v[(size_t)u * BN];
    }
}

__device__ __forceinline__ unsigned process16(const Buf& b, float beta, float& m) {
    unsigned mask = 0u;
#pragma unroll
    for (int u = 0; u < U; ++u) {
        m = fmaf(beta, m, b.c[u]);
        mask |= (m >= b.v[u]) ? (1u << u) : 0u;
    }
    return mask;
}

__global__ __launch_bounds__(512, 2) void snn_fused_fb(
        const float* __restrict__ cur, const float* __restrict__ beta,
        const float* __restrict__ vini, const float* __restrict__ vth,
        float* __restrict__ gz, float* __restrict__ zo, float* __restrict__ ml)
{
    __shared__ unsigned bits[T_LEN / 32][64];
    const int lane = threadIdx.x & 63;
    const int wave = threadIdx.x >> 6;
    const int i = blockIdx.x * 64 + lane;

    if (wave == 0) {
        const float bta = beta[i & (N_IN - 1)];
        float m = vini[i];
        const float* cp = cur + i;
        const float* vp = vth + i;
        Buf b0, b1, b2, b3;
        prefetch(b0, cp, vp, 0);     prefetch(b1, cp, vp, U);
        prefetch(b2, cp, vp, 2 * U); prefetch(b3, cp, vp, 3 * U);
        for (int t0 = 0; t0 < T_LEN; t0 += 4 * U) {
            unsigned m0 = process16(b0, bta, m); prefetch(b0, cp, vp, t0 + 4 * U);
            unsigned m1 = process16(b1, bta, m); prefetch(b1, cp, vp, t0 + 5 * U);
            bits[t0 >> 5][lane] = m0 | (m1 << 16);
            unsigned m2 = process16(b2, bta, m); prefetch(b2, cp, vp, t0 + 6 * U);
            unsigned m3 = process16(b3, bta, m); prefetch(b3, cp, vp, t0 + 7 * U);
            bits[(t0 >> 5) + 1][lane] = m2 | (m3 << 16);
        }
        ml[i] = m;
    }
    __syncthreads();

    int C = 0, Z = 0;
    const int d0 = wave * 4;
    for (int d = 0; d < d0; ++d) {
        unsigned u = bits[d][lane];
#pragma unroll
        for (int b = 0; b < 32; ++b) { C += (u >> b) & 1u; Z += C; }
    }
    float* __restrict__ gp = gz + (size_t)(d0 * 32) * BN + i;
    float* __restrict__ zp = zo + (size_t)(d0 * 32) * BN + i;
    for (int d = 0; d < 4; ++d) {
        unsigned u = bits[d0 + d][lane];
#pragma unroll
        for (int b = 0; b < 32; ++b) {
            C += (u >> b) & 1u;
            Z += C;
            const size_t off = (size_t)(d * 32 + b) * BN;
            gp[off] = (Z == 1) ? 1.0f : 0.0f;
            zp[off] = (float)Z;
        }
    }
}

extern "C" void kernel_launch(void* const* d_in, const int* in_sizes, int n_in,
                              void* d_out, int out_size, void* d_ws, size_t ws_size,
                              hipStream_t stream) {
    const float* cur  = (const float*)d_in[0];   // (T,B,N) fp32
    const float* beta = (const float*)d_in[1];   // (N,)
    const float* vini = (const float*)d_in[2];   // (B,N)
    const float* vth  = (const float*)d_in[3];   // (T,B,N)
    float* gz = (float*)d_out;                       // (T,B,N)
    float* zo = gz + (size_t)T_LEN * BN;             // (T,B,N)
    float* ml = zo + (size_t)T_LEN * BN;             // (B,N)

    const size_t need = (size_t)DW * BN * sizeof(unsigned) * 2;   // 4 MB

    if (d_ws != nullptr && ws_size >= need) {
        unsigned* bitsg = (unsigned*)d_ws;
        unsigned* Pc = bitsg + (size_t)DW * BN;
        snn_scan_wide<<<NBLK1, 768, 0, stream>>>(cur, beta, vini, vth,
                                                 bitsg, Pc, ml);
        snn_expand<<<DW * (BN / 256), 256, 0, stream>>>(bitsg, Pc, gz, zo);
    } else {
        snn_fused_fb<<<BN / 64, 512, 0, stream>>>(cur, beta, vini, vth,
                                                  gz, zo, ml);
    }
}

// Round 13
// 253.450 us; speedup vs baseline: 1.1632x; 1.0545x over previous
//
#include <hip/hip_runtime.h>

// SNN membrane scan + spike + double-cumsum, two-pass, per-CU-BW-saturating.
// R12 design resubmitted with BOUNDED spin guards: a genuine deadlock now
// surfaces as a wrong answer (visible) instead of a hung container.
//
// Pass 1  snn_scan3 (256 blk x 192 thr = 3 waves, 64 ch/block):
//   waves 1,2: loaders (cur, vth). global_load_lds 16B/lane (1 KB/instr,
//              linear [t][ch] dest), ring of 8 x 16-t segments, free-running
//              flag/poll (no barriers), counted vmcnt(12) publication
//              (3 segs always in flight, never drained in steady state).
//   wave 0:    scan. Polls flags, bulk ds_read 16-t window to regs
//              (conflict-free), exact chain, emits spike bitmask + packed
//              carry C|Z<<11 (R4-verified format). Never touches vmcnt.
// Pass 2  snn_expand (2048 blk x 256 thr): verbatim R4 (verified ~26 us).
// Fallback (ws < 4 MB): R1-style single-kernel two-phase (verified, no ws).
//
// fmaf order + integer cumsums identical to all passing rounds -> bit-exact.

#define T_LEN 1024
#define N_IN  512
#define BN    16384           // BATCH * N_IN
#define DW    (T_LEN / 32)    // 32 bit-dwords per channel

// ---- pass 1 geometry ----
#define P1_SEGT 16            // timesteps per segment
#define P1_NSEG (T_LEN / P1_SEGT)   // 64
#define P1_RING 8             // ring depth (segments per array)
#define P1_DEP  3             // segments kept in flight beyond current

// Bounded spin: ~260K sleeps (~15 ms) then proceed -> deadlock becomes a
// visible wrong answer instead of a dead container.
#define SPIN_WHILE(cond) do { unsigned _g = 0;                               \
        while ((cond) && (++_g < (1u << 18))) __builtin_amdgcn_s_sleep(1);   \
        asm volatile("" ::: "memory"); } while (0)

// ---------------- global->LDS direct copy (16 B per lane, linear dest) ------
__device__ __forceinline__ void gload_lds16(const float* g, float* l) {
    __builtin_amdgcn_global_load_lds(
        (const __attribute__((address_space(1))) void*)g,
        (__attribute__((address_space(3))) void*)l, 16, 0, 0);
}

__global__ __launch_bounds__(192, 1) void snn_scan3(
        const float* __restrict__ cur, const float* __restrict__ beta,
        const float* __restrict__ vini, const float* __restrict__ vth,
        unsigned* __restrict__ bitsg, unsigned* __restrict__ Pc,
        float* __restrict__ ml)
{
    __shared__ float ldsC[P1_RING][P1_SEGT * 64];   // 32 KB cur ring
    __shared__ float ldsV[P1_RING][P1_SEGT * 64];   // 32 KB vth ring
    __shared__ volatile int prodC, prodV, consS;

    const int lane   = threadIdx.x & 63;
    const int wave   = threadIdx.x >> 6;    // 0 = scan, 1 = cur ldr, 2 = vth ldr
    const int chbase = blockIdx.x * 64;

    if (threadIdx.x == 0) { prodC = 0; prodV = 0; consS = 0; }
    __syncthreads();                        // one-time init

    if (wave >= 1) {
        // ----------------------------- loaders ------------------------------
        const float* __restrict__ src = (wave == 1) ? cur : vth;
        float* ring = (wave == 1) ? &ldsC[0][0] : &ldsV[0][0];
        volatile int* prod = (wave == 1) ? &prodC : &prodV;
        // lane covers t-row (lane>>4), channels 4*(lane&15)..+3
        const size_t goff = (size_t)chbase + (size_t)(lane >> 4) * BN
                          + (size_t)(4 * (lane & 15));

#pragma unroll 1
        for (int s = 0; s < P1_NSEG; ++s) {
            if (s >= P1_RING)               // ring gate: slot's old seg consumed
                SPIN_WHILE(consS < s - P1_RING + 1);
            float* dst = ring + (s & (P1_RING - 1)) * (P1_SEGT * 64);
#pragma unroll
            for (int j = 0; j < P1_SEGT / 4; ++j)   // 4 x 1KB instructions
                gload_lds16(src + (size_t)(s * P1_SEGT + 4 * j) * BN + goff,
                            dst + j * 256);
            if (s >= P1_DEP) {              // counted publish: 3 segs in flight
                asm volatile("s_waitcnt vmcnt(12)" ::: "memory");
                *prod = s - P1_DEP + 1;
            }
        }
        asm volatile("s_waitcnt vmcnt(8)" ::: "memory"); *prod = P1_NSEG - 2;
        asm volatile("s_waitcnt vmcnt(4)" ::: "memory"); *prod = P1_NSEG - 1;
        asm volatile("s_waitcnt vmcnt(0)" ::: "memory"); *prod = P1_NSEG;
    } else {
        // ----------------------------- scan wave ----------------------------
        const int i = chbase + lane;
        const float bta = beta[i & (N_IN - 1)];
        float m = vini[i];
        int C = 0, Z = 0;
        unsigned mlo = 0u;

#pragma unroll 1
        for (int s = 0; s < P1_NSEG; ++s) {
            SPIN_WHILE(prodC < s + 1 || prodV < s + 1);
            const int sl = s & (P1_RING - 1);
            const float* lc = &ldsC[sl][lane];
            const float* lv = &ldsV[sl][lane];

            if ((s & 1) == 0)   // carry state BEFORE t = 32*(s/2)
                Pc[(size_t)(s >> 1) * BN + i] =
                    (unsigned)C | ((unsigned)Z << 11);

            float cc[P1_SEGT], vv[P1_SEGT];
#pragma unroll
            for (int t = 0; t < P1_SEGT; ++t) {   // conflict-free bulk window
                cc[t] = lc[t * 64];
                vv[t] = lv[t * 64];
            }
            unsigned mask = 0u;
#pragma unroll
            for (int t = 0; t < P1_SEGT; ++t) {
                m = fmaf(bta, m, cc[t]);              // exact same op/order
                const int sp = (m >= vv[t]) ? 1 : 0;  // Heaviside(m - vth)
                mask |= (unsigned)sp << t;
                C += sp;                              // c1 cumsum (exact int)
                Z += C;                               // z double-cumsum (exact)
            }
            if ((s & 1) == 0) mlo = mask;
            else bitsg[(size_t)(s >> 1) * BN + i] = mlo | (mask << 16);

            // all ds_reads done before releasing the slot:
            asm volatile("s_waitcnt lgkmcnt(0)" ::: "memory");
            if (lane == 0) consS = s + 1;
        }
        ml[i] = m;                                    // m_last (B,N)
    }
}

// -------------------------- pass 2: expand (R4, verified) -------------------
__global__ __launch_bounds__(256, 4) void snn_expand(
        const unsigned* __restrict__ bitsg, const unsigned* __restrict__ Pc,
        float* __restrict__ gz, float* __restrict__ zo)
{
    const int d  = blockIdx.x & (DW - 1);   // t-dword 0..31
    const int cb = blockIdx.x / DW;         // channel block 0..63
    const int cg = threadIdx.x & 63;        // 4-channel group within 256
    const int tt = threadIdx.x >> 6;        // wave id 0..3 -> owns 8 t-rows
    const int ch = cb * 256 + cg * 4;       // first of 4 consecutive channels

    const uint4 u  = *reinterpret_cast<const uint4*>(&bitsg[(size_t)d * BN + ch]);
    const uint4 p4 = *reinterpret_cast<const uint4*>(&Pc[(size_t)d * BN + ch]);
    int C0 = (int)(p4.x & 0x7FFu), Z0 = (int)(p4.x >> 11);
    int C1 = (int)(p4.y & 0x7FFu), Z1 = (int)(p4.y >> 11);
    int C2 = (int)(p4.z & 0x7FFu), Z2 = (int)(p4.z >> 11);
    int C3 = (int)(p4.w & 0x7FFu), Z3 = (int)(p4.w >> 11);

    const int pre = tt * 8;                 // replay bits [0, pre) exactly
    for (int b = 0; b < pre; ++b) {
        C0 += (int)((u.x >> b) & 1u); Z0 += C0;
        C1 += (int)((u.y >> b) & 1u); Z1 += C1;
        C2 += (int)((u.z >> b) & 1u); Z2 += C2;
        C3 += (int)((u.w >> b) & 1u); Z3 += C3;
    }

    float* __restrict__ gp = gz + (size_t)(d * 32 + pre) * BN + ch;
    float* __restrict__ zp = zo + (size_t)(d * 32 + pre) * BN + ch;
#pragma unroll
    for (int r = 0; r < 8; ++r) {           // my 8 t-rows: t = 32d + pre + r
        const int b = pre + r;
        C0 += (int)((u.x >> b) & 1u); Z0 += C0;
        C1 += (int)((u.y >> b) & 1u); Z1 += C1;
        C2 += (int)((u.z >> b) & 1u); Z2 += C2;
        C3 += (int)((u.w >> b) & 1u); Z3 += C3;
        const float4 gf = make_float4(Z0 == 1 ? 1.0f : 0.0f,
                                      Z1 == 1 ? 1.0f : 0.0f,
                                      Z2 == 1 ? 1.0f : 0.0f,
                                      Z3 == 1 ? 1.0f : 0.0f);
        const float4 zf = make_float4((float)Z0, (float)Z1,
                                      (float)Z2, (float)Z3);
        *reinterpret_cast<float4*>(gp + (size_t)r * BN) = gf;   // Block.g fwd
        *reinterpret_cast<float4*>(zp + (size_t)r * BN) = zf;   // exact: z < 2^21
    }
}

// ---------------------- fallback (no workspace; R1-verified) ----------------
#define U 16
struct Buf { float c[U]; float v[U]; };

__device__ __forceinline__ void prefetch(Buf& b, const float* __restrict__ cp,
                                         const float* __restrict__ vp, int t0) {
    if (t0 >= T_LEN) return;
    const float* __restrict__ c = cp + (size_t)t0 * BN;
    const float* __restrict__ v = vp + (size_t)t0 * BN;
#pragma unroll
    for (int u = 0; u < U; ++u) {
        b.c[u] = c[(size_t)u * BN];
        b.v[u] = v[(size_t)u * BN];
    }
}

__device__ __forceinline__ unsigned process16(const Buf& b, float beta, float& m) {
    unsigned mask = 0u;
#pragma unroll
    for (int u = 0; u < U; ++u) {
        m = fmaf(beta, m, b.c[u]);
        mask |= (m >= b.v[u]) ? (1u << u) : 0u;
    }
    return mask;
}

__global__ __launch_bounds__(512, 2) void snn_fused_fb(
        const float* __restrict__ cur, const float* __restrict__ beta,
        const float* __restrict__ vini, const float* __restrict__ vth,
        float* __restrict__ gz, float* __restrict__ zo, float* __restrict__ ml)
{
    __shared__ unsigned bits[T_LEN / 32][64];
    const int lane = threadIdx.x & 63;
    const int wave = threadIdx.x >> 6;
    const int i = blockIdx.x * 64 + lane;

    if (wave == 0) {
        const float bta = beta[i & (N_IN - 1)];
        float m = vini[i];
        const float* cp = cur + i;
        const float* vp = vth + i;
        Buf b0, b1, b2, b3;
        prefetch(b0, cp, vp, 0);     prefetch(b1, cp, vp, U);
        prefetch(b2, cp, vp, 2 * U); prefetch(b3, cp, vp, 3 * U);
        for (int t0 = 0; t0 < T_LEN; t0 += 4 * U) {
            unsigned m0 = process16(b0, bta, m); prefetch(b0, cp, vp, t0 + 4 * U);
            unsigned m1 = process16(b1, bta, m); prefetch(b1, cp, vp, t0 + 5 * U);
            bits[t0 >> 5][lane] = m0 | (m1 << 16);
            unsigned m2 = process16(b2, bta, m); prefetch(b2, cp, vp, t0 + 6 * U);
            unsigned m3 = process16(b3, bta, m); prefetch(b3, cp, vp, t0 + 7 * U);
            bits[(t0 >> 5) + 1][lane] = m2 | (m3 << 16);
        }
        ml[i] = m;
    }
    __syncthreads();

    int C = 0, Z = 0;
    const int d0 = wave * 4;
    for (int d = 0; d < d0; ++d) {
        unsigned u = bits[d][lane];
#pragma unroll
        for (int b = 0; b < 32; ++b) { C += (u >> b) & 1u; Z += C; }
    }
    float* __restrict__ gp = gz + (size_t)(d0 * 32) * BN + i;
    float* __restrict__ zp = zo + (size_t)(d0 * 32) * BN + i;
    for (int d = 0; d < 4; ++d) {
        unsigned u = bits[d0 + d][lane];
#pragma unroll
        for (int b = 0; b < 32; ++b) {
            C += (u >> b) & 1u;
            Z += C;
            const size_t off = (size_t)(d * 32 + b) * BN;
            gp[off] = (Z == 1) ? 1.0f : 0.0f;
            zp[off] = (float)Z;
        }
    }
}

extern "C" void kernel_launch(void* const* d_in, const int* in_sizes, int n_in,
                              void* d_out, int out_size, void* d_ws, size_t ws_size,
                              hipStream_t stream) {
    const float* cur  = (const float*)d_in[0];   // (T,B,N) fp32
    const float* beta = (const float*)d_in[1];   // (N,)
    const float* vini = (const float*)d_in[2];   // (B,N)
    const float* vth  = (const float*)d_in[3];   // (T,B,N)
    float* gz = (float*)d_out;                       // (T,B,N)
    float* zo = gz + (size_t)T_LEN * BN;             // (T,B,N)
    float* ml = zo + (size_t)T_LEN * BN;             // (B,N)

    const size_t need = (size_t)DW * BN * sizeof(unsigned) * 2;   // 4 MB

    if (d_ws != nullptr && ws_size >= need) {
        unsigned* bitsg = (unsigned*)d_ws;
        unsigned* Pc = bitsg + (size_t)DW * BN;
        snn_scan3<<<BN / 64, 192, 0, stream>>>(cur, beta, vini, vth,
                                               bitsg, Pc, ml);
        snn_expand<<<DW * (BN / 256), 256, 0, stream>>>(bitsg, Pc, gz, zo);
    } else {
        snn_fused_fb<<<BN / 64, 512, 0, stream>>>(cur, beta, vini, vth,
                                                  gz, zo, ml);
    }
}